// Round 5
// baseline (191.392 us; speedup 1.0000x reference)
//
#include <hip/hip_runtime.h>

#define SEQ 41
#define FEAT 128
#define KDIM 384
#define ROWLEN (SEQ * FEAT)        // 5248 floats per batch row
#define BM 256                     // rows per block = 16 waves x 16 rows

typedef float floatx4 __attribute__((ext_vector_type(4)));
typedef __bf16 bf16x8 __attribute__((ext_vector_type(8)));
typedef unsigned short ushortx8 __attribute__((ext_vector_type(8)));

// fp32 -> bf16 bits, round-to-nearest-even (prepass / fallback path)
__device__ __forceinline__ unsigned short f2bf(float f) {
    unsigned int u = __builtin_bit_cast(unsigned int, f);
    return (unsigned short)((u + 0x7fffu + ((u >> 16) & 1u)) >> 16);
}

// pack 8 fp32 (k = quad*8 + j) into one MFMA A-fragment (RTNE via native casts)
__device__ __forceinline__ bf16x8 pack8(floatx4 lo, floatx4 hi) {
    bf16x8 r;
#pragma unroll
    for (int j = 0; j < 4; j++) { r[j] = (__bf16)lo[j]; r[4 + j] = (__bf16)hi[j]; }
    return r;
}

// async global->LDS DMA, 16 B per lane; LDS dest = uniform base + lane*16
#define DMA16(g, l)                                                          \
    __builtin_amdgcn_global_load_lds(                                        \
        (const __attribute__((address_space(1))) void*)(g),                  \
        (__attribute__((address_space(3))) void*)(l), 16, 0, 0)

// ---------------- prepass: W[s][k][n] fp32 -> Wt2 in MFMA fragment order --------
// Wt2 linear layout: [s][slab(6)][ks(2)][nt(8)][lane(64)][8 bf16]
//   n = nt*16 + (lane&15);  k = slab*64 + ks*32 + (lane>>4)*8 + j
__global__ __launch_bounds__(256) void wt2_kernel(const float* __restrict__ W,
                                                  unsigned short* __restrict__ Wt2) {
    int t = blockIdx.x * 256 + threadIdx.x;   // exactly 41*6144 threads
    int s = t / 6144, g = t % 6144;
    int lane = g & 63, nt = (g >> 6) & 7, ks = (g >> 9) & 1, slab = g >> 10;
    int n  = nt * 16 + (lane & 15);
    int k0 = slab * 64 + ks * 32 + (lane >> 4) * 8;
    const float* Ws = W + (size_t)s * KDIM * FEAT;
    ushortx8 v;
#pragma unroll
    for (int j = 0; j < 8; j++) v[j] = f2bf(Ws[(size_t)(k0 + j) * FEAT + n]);
    *reinterpret_cast<ushortx8*>(Wt2 + (size_t)t * 8) = v;
}

// ---------------- main GEMM ----------------
// 1024 thr = 16 waves; each wave owns a 16x128 tile of a 256x128 block tile
// for one s (4 waves/SIMD). B (whole K, fragment order) staged once into 96 KB
// LDS via global_load_lds, ONE barrier, then a barrier-free K-loop: B via
// contiguous ds_read_b128, A register-prefetched 4 ks-steps deep from X.
//
// Grid is s-FASTEST (grid = (SEQ, nbx)): the ~256 concurrently-resident blocks
// cover ALL 41 s-chunks of each resident row-panel, so the 512 B-per-(m,s)
// output chunks combine into full 21 KB contiguous row coverage at the memory
// controller (r0-r4 invariant: eff. DRAM BW stuck at 2.3 TB/s with bx-fastest
// ordering -> write-granule theory). Output stores are non-temporal (never
// re-read) so they don't evict X/Wt2 from L2/L3.
template <int USE_WT>
__global__ __launch_bounds__(1024, 4) void gemm_kernel(const float* __restrict__ X,
                                                       const void* __restrict__ Wsrc,
                                                       const float* __restrict__ bias,
                                                       float* __restrict__ out) {
    __shared__ unsigned short Bs[6 * 8192];   // 96 KB, [ksi(12)][nt(8)][lane(64)][8 bf16]

    const int tid  = threadIdx.x;
    const int lane = tid & 63;
    const int wv   = tid >> 6;                // 0..15
    const int s    = blockIdx.x;              // s-fastest
    const int m0   = blockIdx.y * BM + wv * 16;

    // OOB window cols form whole 64-float slabs -> restrict K-range, no bounds checks
    const int klo = (s == 0) ? 2 : 0;
    const int khi = (s == SEQ - 1) ? 4 : 6;
    const int nk  = khi - klo;                // 4 or 6 K=64 slabs
    const int nst = nk * 2;                   // K=32 steps: 8 or 12 (multiple of 4)

    const int colq = lane & 15, quad = lane >> 4;

    // A: lane holds row (lane&15), k = quad*8 + j (8 contiguous fp32); koff >= 0 always
    const int koff = (s - 1) * FEAT + klo * 64 + quad * 8;
    const float* aptr = X + (size_t)(m0 + colq) * ROWLEN + koff;

    floatx4 acc[8];
#pragma unroll
    for (int ni = 0; ni < 8; ni++) acc[ni] = (floatx4){0.f, 0.f, 0.f, 0.f};

    // 4-deep register A pipeline; struct members keep all indices static (no scratch)
    struct Abuf { floatx4 L, H; };
    Abuf A0, A1, A2, A3;

    auto loadA = [&](Abuf& ab, int ksi) {
        const float* p = aptr + ksi * 32;
        ab.L = *reinterpret_cast<const floatx4*>(p);
        ab.H = *reinterpret_cast<const floatx4*>(p + 4);
    };

    auto step = [&](const Abuf& ab, int ksi) {
        const unsigned short* bp = &Bs[ksi * 4096 + lane * 8];
        bf16x8 af = pack8(ab.L, ab.H);
        bf16x8 bfr[8];
#pragma unroll
        for (int ni = 0; ni < 8; ni++)
            bfr[ni] = *reinterpret_cast<const bf16x8*>(bp + ni * 512);
        __builtin_amdgcn_s_setprio(1);
#pragma unroll
        for (int ni = 0; ni < 8; ni++)
            acc[ni] = __builtin_amdgcn_mfma_f32_16x16x32_bf16(af, bfr[ni], acc[ni], 0, 0, 0);
        __builtin_amdgcn_s_setprio(0);
    };

    // ---- prologue: A pipeline fill + whole-K B staging, single barrier ----
    loadA(A0, 0); loadA(A1, 1); loadA(A2, 2); loadA(A3, 3);

    if (USE_WT) {
        const unsigned short* wsrc =
            (const unsigned short*)Wsrc + ((size_t)s * 6 + klo) * 8192;
        const int nwi = nk * 16;              // 64-96 fragments of 1 KB
        for (int i = wv; i < nwi; i += 16)
            DMA16(wsrc + (size_t)i * 512 + lane * 8, &Bs[(size_t)i * 512]);
    } else {
        // fallback: gather from fp32 W[s][k][n] into fragment order (correctness path)
        const float* Wf = (const float*)Wsrc;
        for (int j = tid; j < nk * 1024; j += 1024) {
            int ln = j & 63, nt = (j >> 6) & 7, ksa = j >> 9;
            int k = klo * 64 + ksa * 32 + (ln >> 4) * 8;
            int n = nt * 16 + (ln & 15);
            ushortx8 v;
#pragma unroll
            for (int jj = 0; jj < 8; jj++)
                v[jj] = f2bf(Wf[((size_t)s * KDIM + k + jj) * FEAT + n]);
            *reinterpret_cast<ushortx8*>(&Bs[(size_t)j * 8]) = v;
        }
    }
    __syncthreads();                          // the ONLY barrier

    // ---- barrier-free K-loop, A prefetched 4 ks-steps ahead ----
    int ksi = 0;
    for (; ksi + 4 < nst; ksi += 4) {
        step(A0, ksi + 0); loadA(A0, ksi + 4);
        step(A1, ksi + 1); loadA(A1, ksi + 5);
        step(A2, ksi + 2); loadA(A2, ksi + 6);
        step(A3, ksi + 3); loadA(A3, ksi + 7);
    }
    step(A0, ksi + 0); step(A1, ksi + 1); step(A2, ksi + 2); step(A3, ksi + 3);

    // ---- epilogue: bias + relu; C layout: col = lane&15, row = quad*4 + r ----
    // non-temporal: output is never re-read; keep L2/L3 for X and Wt2
#pragma unroll
    for (int ni = 0; ni < 8; ni++) {
        int n = ni * 16 + colq;
        float bv = bias[s * FEAT + n];
        size_t base = ((size_t)(m0 + quad * 4) * SEQ + s) * FEAT + n;
#pragma unroll
        for (int r = 0; r < 4; r++) {
            float v = acc[ni][r] + bv;
            v = v > 0.f ? v : 0.f;
            __builtin_nontemporal_store(v, &out[base + (size_t)r * (SEQ * FEAT)]);
        }
    }
}

extern "C" void kernel_launch(void* const* d_in, const int* in_sizes, int n_in,
                              void* d_out, int out_size, void* d_ws, size_t ws_size,
                              hipStream_t stream) {
    const float* X    = (const float*)d_in[0];
    const float* W    = (const float*)d_in[1];
    const float* bias = (const float*)d_in[2];
    float* out = (float*)d_out;

    const int B = in_sizes[0] / ROWLEN;               // 4096
    dim3 grid(SEQ, B / BM);                           // (41, 16): s-fastest

    const size_t wt_bytes = (size_t)SEQ * 6 * 8192 * sizeof(unsigned short);  // ~4 MB
    if (ws_size >= wt_bytes) {
        unsigned short* Wt2 = (unsigned short*)d_ws;
        wt2_kernel<<<(SEQ * 6144) / 256, 256, 0, stream>>>(W, Wt2);
        gemm_kernel<1><<<grid, 1024, 0, stream>>>(X, (const void*)Wt2, bias, out);
    } else {
        gemm_kernel<0><<<grid, 1024, 0, stream>>>(X, (const void*)W, bias, out);
    }
}

// Round 6
// 184.579 us; speedup vs baseline: 1.0369x; 1.0369x over previous
//
#include <hip/hip_runtime.h>

#define SEQ 41
#define FEAT 128
#define KDIM 384
#define ROWLEN (SEQ * FEAT)        // 5248 floats per batch row
#define BM 128                     // rows per block = 8 waves x 16 rows

typedef float floatx4 __attribute__((ext_vector_type(4)));
typedef __bf16 bf16x8 __attribute__((ext_vector_type(8)));
typedef unsigned short ushortx8 __attribute__((ext_vector_type(8)));

// fp32 -> bf16 bits, round-to-nearest-even (prepass / fallback path)
__device__ __forceinline__ unsigned short f2bf(float f) {
    unsigned int u = __builtin_bit_cast(unsigned int, f);
    return (unsigned short)((u + 0x7fffu + ((u >> 16) & 1u)) >> 16);
}

// pack 8 fp32 (k = quad*8 + j) into one MFMA A-fragment (RTNE via native casts)
__device__ __forceinline__ bf16x8 pack8(floatx4 lo, floatx4 hi) {
    bf16x8 r;
#pragma unroll
    for (int j = 0; j < 4; j++) { r[j] = (__bf16)lo[j]; r[4 + j] = (__bf16)hi[j]; }
    return r;
}

// async global->LDS DMA, 16 B per lane; LDS dest = uniform base + lane*16
#define DMA16(g, l)                                                          \
    __builtin_amdgcn_global_load_lds(                                        \
        (const __attribute__((address_space(1))) void*)(g),                  \
        (__attribute__((address_space(3))) void*)(l), 16, 0, 0)

// ---------------- prepass: W[s][k][n] fp32 -> Wt2 in MFMA fragment order --------
// Wt2 linear layout: [s][slab(6)][ks(2)][nt(8)][lane(64)][8 bf16]
//   n = nt*16 + (lane&15);  k = slab*64 + ks*32 + (lane>>4)*8 + j
__global__ __launch_bounds__(256) void wt2_kernel(const float* __restrict__ W,
                                                  unsigned short* __restrict__ Wt2) {
    int t = blockIdx.x * 256 + threadIdx.x;   // exactly 41*6144 threads
    int s = t / 6144, g = t % 6144;
    int lane = g & 63, nt = (g >> 6) & 7, ks = (g >> 9) & 1, slab = g >> 10;
    int n  = nt * 16 + (lane & 15);
    int k0 = slab * 64 + ks * 32 + (lane >> 4) * 8;
    const float* Ws = W + (size_t)s * KDIM * FEAT;
    ushortx8 v;
#pragma unroll
    for (int j = 0; j < 8; j++) v[j] = f2bf(Ws[(size_t)(k0 + j) * FEAT + n]);
    *reinterpret_cast<ushortx8*>(Wt2 + (size_t)t * 8) = v;
}

// ---------------- main GEMM ----------------
// 512 thr = 8 waves; each wave owns a 16x128 tile of a 128x128 block tile for
// one s. B (whole K, fragment order) staged once into 96 KB LDS, ONE barrier,
// barrier-free K-loop (contiguous ds_read_b128 B, 4-deep register A-prefetch).
//
// Block-ID decode (r5 fabric theory): with round-robin workgroup->XCD dispatch
// (bid&7 = xcd), each XCD processes its OWN 4 panels through s-chunks of 7:
// the 28 co-resident blocks per XCD = {4 panels} x {7 consecutive s}, working
// set ~3.1 MB < 4 MB L2. The three s-neighbor consumers of every X byte and
// the 4 same-s panels sharing W[s] all hit the SAME L2 -> fabric traffic drops
// from ~420 MB (all rounds so far, ~5.5 TB/s saturated) to ~200 MB.
template <int USE_WT>
__global__ __launch_bounds__(512, 2) void gemm_kernel(const float* __restrict__ X,
                                                      const void* __restrict__ Wsrc,
                                                      const float* __restrict__ bias,
                                                      float* __restrict__ out) {
    __shared__ unsigned short Bs[6 * 8192];   // 96 KB, [ksi(12)][nt(8)][lane(64)][8 bf16]

    // ---- per-XCD (panel-group x s-chunk) decode ----
    const int nbx = (int)gridDim.x / SEQ;     // panels (32)
    int panel, s;
    if ((nbx & 7) == 0) {
        const int npx  = nbx >> 3;            // panels per XCD (4)
        const int xcd  = (int)blockIdx.x & 7; // round-robin dispatch assumption
        const int k    = (int)blockIdx.x >> 3;// this XCD's sequence index
        const int full = 7 * npx;             // blocks per full s-chunk
        int c = k / full;                     // s-chunk 0..5 (sizes 7,7,7,7,7,6)
        int j = k - c * full;
        int q = j / npx;
        s     = c * 7 + q;                    // consecutive s co-resident
        panel = xcd * npx + (j - q * npx);    // 4 fixed panels per XCD
    } else {
        panel = (int)blockIdx.x % nbx; s = (int)blockIdx.x / nbx;
    }

    const int tid  = threadIdx.x;
    const int lane = tid & 63;
    const int wv   = tid >> 6;                // 0..7
    const int m0   = panel * BM + wv * 16;

    // OOB window cols form whole 64-float slabs -> restrict K-range, no bounds checks
    const int klo = (s == 0) ? 2 : 0;
    const int khi = (s == SEQ - 1) ? 4 : 6;
    const int nk  = khi - klo;                // 4 or 6 K=64 slabs
    const int nst = nk * 2;                   // K=32 steps: 8 or 12 (multiple of 4)

    const int colq = lane & 15, quad = lane >> 4;

    // A: lane holds row (lane&15), k = quad*8 + j (8 contiguous fp32); koff >= 0 always
    const int koff = (s - 1) * FEAT + klo * 64 + quad * 8;
    const float* aptr = X + (size_t)(m0 + colq) * ROWLEN + koff;

    floatx4 acc[8];
#pragma unroll
    for (int ni = 0; ni < 8; ni++) acc[ni] = (floatx4){0.f, 0.f, 0.f, 0.f};

    // 4-deep register A pipeline; struct members keep all indices static (no scratch)
    struct Abuf { floatx4 L, H; };
    Abuf A0, A1, A2, A3;

    auto loadA = [&](Abuf& ab, int ksi) {
        const float* p = aptr + ksi * 32;
        ab.L = *reinterpret_cast<const floatx4*>(p);
        ab.H = *reinterpret_cast<const floatx4*>(p + 4);
    };

    auto step = [&](const Abuf& ab, int ksi) {
        const unsigned short* bp = &Bs[ksi * 4096 + lane * 8];
        bf16x8 af = pack8(ab.L, ab.H);
        bf16x8 bfr[8];
#pragma unroll
        for (int ni = 0; ni < 8; ni++)
            bfr[ni] = *reinterpret_cast<const bf16x8*>(bp + ni * 512);
        __builtin_amdgcn_s_setprio(1);
#pragma unroll
        for (int ni = 0; ni < 8; ni++)
            acc[ni] = __builtin_amdgcn_mfma_f32_16x16x32_bf16(af, bfr[ni], acc[ni], 0, 0, 0);
        __builtin_amdgcn_s_setprio(0);
    };

    // ---- prologue: A pipeline fill + whole-K B staging, single barrier ----
    loadA(A0, 0); loadA(A1, 1); loadA(A2, 2); loadA(A3, 3);

    if (USE_WT) {
        const unsigned short* wsrc =
            (const unsigned short*)Wsrc + ((size_t)s * 6 + klo) * 8192;
        const int nwi = nk * 16;              // 64-96 fragments of 1 KB
        for (int i = wv; i < nwi; i += 8)
            DMA16(wsrc + (size_t)i * 512 + lane * 8, &Bs[(size_t)i * 512]);
    } else {
        // fallback: gather from fp32 W[s][k][n] into fragment order (correctness path)
        const float* Wf = (const float*)Wsrc;
        for (int j = tid; j < nk * 1024; j += 512) {
            int ln = j & 63, nt = (j >> 6) & 7, ksa = j >> 9;
            int k = klo * 64 + ksa * 32 + (ln >> 4) * 8;
            int n = nt * 16 + (ln & 15);
            ushortx8 v;
#pragma unroll
            for (int jj = 0; jj < 8; jj++)
                v[jj] = f2bf(Wf[((size_t)s * KDIM + k + jj) * FEAT + n]);
            *reinterpret_cast<ushortx8*>(&Bs[(size_t)j * 8]) = v;
        }
    }
    __syncthreads();                          // the ONLY barrier

    // ---- barrier-free K-loop, A prefetched 4 ks-steps ahead ----
    int ksi = 0;
    for (; ksi + 4 < nst; ksi += 4) {
        step(A0, ksi + 0); loadA(A0, ksi + 4);
        step(A1, ksi + 1); loadA(A1, ksi + 5);
        step(A2, ksi + 2); loadA(A2, ksi + 6);
        step(A3, ksi + 3); loadA(A3, ksi + 7);
    }
    step(A0, ksi + 0); step(A1, ksi + 1); step(A2, ksi + 2); step(A3, ksi + 3);

    // ---- epilogue: bias + relu; C layout: col = lane&15, row = quad*4 + r ----
#pragma unroll
    for (int ni = 0; ni < 8; ni++) {
        int n = ni * 16 + colq;
        float bv = bias[s * FEAT + n];
        size_t base = ((size_t)(m0 + quad * 4) * SEQ + s) * FEAT + n;
#pragma unroll
        for (int r = 0; r < 4; r++) {
            float v = acc[ni][r] + bv;
            v = v > 0.f ? v : 0.f;
            out[base + (size_t)r * (SEQ * FEAT)] = v;
        }
    }
}

extern "C" void kernel_launch(void* const* d_in, const int* in_sizes, int n_in,
                              void* d_out, int out_size, void* d_ws, size_t ws_size,
                              hipStream_t stream) {
    const float* X    = (const float*)d_in[0];
    const float* W    = (const float*)d_in[1];
    const float* bias = (const float*)d_in[2];
    float* out = (float*)d_out;

    const int B = in_sizes[0] / ROWLEN;               // 4096
    const int nbx = B / BM;                           // 32 panels
    dim3 grid(nbx * SEQ);                             // 1-D, per-XCD chunk decode

    const size_t wt_bytes = (size_t)SEQ * 6 * 8192 * sizeof(unsigned short);  // ~4 MB
    if (ws_size >= wt_bytes) {
        unsigned short* Wt2 = (unsigned short*)d_ws;
        wt2_kernel<<<(SEQ * 6144) / 256, 256, 0, stream>>>(W, Wt2);
        gemm_kernel<1><<<grid, 512, 0, stream>>>(X, (const void*)Wt2, bias, out);
    } else {
        gemm_kernel<0><<<grid, 512, 0, stream>>>(X, (const void*)W, bias, out);
    }
}